// Round 6
// baseline (521.670 us; speedup 1.0000x reference)
//
#include <hip/hip_runtime.h>
#include <math.h>

// Problem constants (reference: N=8192, DIM=512, TOPK=10, all fp32)
#define NROWS 8192
#define DIMK  512
#define TOPK  10
#define SCALE 0.044194173824159223f   // fp32(512**-0.5)

// Phase-1 embed GEMM tiling (fp32 VALU, 128x128 tile, 8x8 micro)
#define ETM 128
#define ETN 128
#define ETK 32
#define NTHREADS 256

// Screen GEMM tiling (bf16 MFMA, one 128x128 tile per block)
#define BM 128
#define BN 128
#define BK 32
#define NQ 256                    // 32-col groups per row (8192/32)
#define CAP 64                    // max candidates per row
#define TMARGIN 2.0f              // bf16-gemm noise (~0.65) + bf16-storage (~0.35) << 2.0

typedef __attribute__((ext_vector_type(8))) short bf16x8;   // 8 bf16 = 4 VGPRs
typedef __attribute__((ext_vector_type(4))) float f32x4;

// ---------------------------------------------------------------------------
// Register-resident sorted top-K (ascending; vals[0] = running min).
// ---------------------------------------------------------------------------
template <int K>
__device__ __forceinline__ void tk_insert(float (&vals)[K], int (&idxs)[K],
                                          float v, int idx) {
  if (v > vals[0]) {
    vals[0] = v; idxs[0] = idx;
#pragma unroll
    for (int s = 0; s < K - 1; ++s) {
      const bool sw = vals[s] > vals[s + 1];
      const float tv = vals[s]; const int ti = idxs[s];
      vals[s]     = sw ? vals[s + 1] : vals[s];
      idxs[s]     = sw ? idxs[s + 1] : idxs[s];
      vals[s + 1] = sw ? tv : vals[s + 1];
      idxs[s + 1] = sw ? ti : idxs[s + 1];
    }
  }
}

template <int K>
__device__ __forceinline__ void tkv_insert(float (&vals)[K], float v) {
  if (v > vals[0]) {
    vals[0] = v;
#pragma unroll
    for (int s = 0; s < K - 1; ++s) {
      const bool sw = vals[s] > vals[s + 1];
      const float tv = vals[s];
      vals[s]     = sw ? vals[s + 1] : vals[s];
      vals[s + 1] = sw ? tv : vals[s + 1];
    }
  }
}

__device__ __forceinline__ unsigned short f2bf(float f) {   // RNE fp32->bf16
  unsigned int u = __float_as_uint(f);
  u = (u + 0x7FFF + ((u >> 16) & 1)) >> 16;
  return (unsigned short)u;
}

// async global->LDS, 16B per lane; lds ptr must be wave-uniform base
__device__ __forceinline__ void gld16(const void* g, const void* lds) {
  __builtin_amdgcn_global_load_lds(
      (const __attribute__((address_space(1))) void*)g,
      (__attribute__((address_space(3))) void*)lds, 16, 0, 0);
}

// ---------------------------------------------------------------------------
// Phase 1: E = X @ W^T + b (fp32 exact) + bf16 copies. 128x128 tile, 8x8
// micro-tile (rows ty*4+{0..3} & +64; cols tx*4+{0..3} & +64 -> B-reads are
// 2-way bank-aliased = free). Per-element k-chain stays sequential ascending
// fmaf -> BIT-IDENTICAL Eh/Et vs prior rounds (rank near-ties depend on it).
// ---------------------------------------------------------------------------
__global__ __launch_bounds__(NTHREADS, 4)
void embed_gemm(const float* __restrict__ X,
                const float* __restrict__ Wh, const float* __restrict__ bh,
                const float* __restrict__ Wt, const float* __restrict__ bt,
                float* __restrict__ Eh, float* __restrict__ Et,
                unsigned short* __restrict__ Ehb, unsigned short* __restrict__ Etb) {
  __shared__ float As[ETK][ETM + 4];   // d-major, 16.9 KB
  __shared__ float Bs[ETK][ETN + 4];

  const int tid = threadIdx.x;
  const int rowBase = blockIdx.x * ETM;
  const int colBase = blockIdx.y * ETN;          // 0..896 over [Wh|Wt]
  const float* W  = (colBase < DIMK) ? Wh : Wt;
  const float* bb = (colBase < DIMK) ? bh : bt;
  float* Out            = (colBase < DIMK) ? Eh : Et;
  unsigned short* Outb  = (colBase < DIMK) ? Ehb : Etb;
  const int colOff = colBase & (DIMK - 1);

  const int tx = tid & 15, ty = tid >> 4;
  float acc[8][8];
#pragma unroll
  for (int r = 0; r < 8; ++r)
#pragma unroll
    for (int c = 0; c < 8; ++c) acc[r][c] = 0.f;

  for (int kt = 0; kt < DIMK; kt += ETK) {
    __syncthreads();   // WAR: previous iteration's reads done before restage
#pragma unroll
    for (int u = 0; u < 4; ++u) {
      const int idx = tid + u * NTHREADS;     // 0..1023
      const int r = idx >> 3;                 // 0..127
      const int dc = idx & 7;                 // k-quad within 32
      const float4 av = *(const float4*)&X[(size_t)(rowBase + r) * DIMK + kt + dc * 4];
      As[dc * 4 + 0][r] = av.x; As[dc * 4 + 1][r] = av.y;
      As[dc * 4 + 2][r] = av.z; As[dc * 4 + 3][r] = av.w;
      const float4 bv = *(const float4*)&W[(size_t)(colOff + r) * DIMK + kt + dc * 4];
      Bs[dc * 4 + 0][r] = bv.x; Bs[dc * 4 + 1][r] = bv.y;
      Bs[dc * 4 + 2][r] = bv.z; Bs[dc * 4 + 3][r] = bv.w;
    }
    __syncthreads();
#pragma unroll 8
    for (int k = 0; k < ETK; ++k) {
      const float4 a0 = *(const float4*)&As[k][ty * 4];
      const float4 a1 = *(const float4*)&As[k][64 + ty * 4];
      const float4 b0 = *(const float4*)&Bs[k][tx * 4];
      const float4 b1 = *(const float4*)&Bs[k][64 + tx * 4];
      const float ar[8] = {a0.x, a0.y, a0.z, a0.w, a1.x, a1.y, a1.z, a1.w};
      const float br[8] = {b0.x, b0.y, b0.z, b0.w, b1.x, b1.y, b1.z, b1.w};
#pragma unroll
      for (int r = 0; r < 8; ++r)
#pragma unroll
        for (int c = 0; c < 8; ++c)
          acc[r][c] = fmaf(ar[r], br[c], acc[r][c]);
    }
  }

  float br[8];
  {
    const float4 bv0 = *(const float4*)&bb[colOff + tx * 4];
    const float4 bv1 = *(const float4*)&bb[colOff + 64 + tx * 4];
    br[0] = bv0.x; br[1] = bv0.y; br[2] = bv0.z; br[3] = bv0.w;
    br[4] = bv1.x; br[5] = bv1.y; br[6] = bv1.z; br[7] = bv1.w;
  }
#pragma unroll
  for (int r = 0; r < 8; ++r) {
    const int row = rowBase + ((r < 4) ? (ty * 4 + r) : (64 + ty * 4 + r - 4));
    float4 o0, o1;
    o0.x = acc[r][0] + br[0]; o0.y = acc[r][1] + br[1];
    o0.z = acc[r][2] + br[2]; o0.w = acc[r][3] + br[3];
    o1.x = acc[r][4] + br[4]; o1.y = acc[r][5] + br[5];
    o1.z = acc[r][6] + br[6]; o1.w = acc[r][7] + br[7];
    const size_t off0 = (size_t)row * DIMK + colOff + tx * 4;
    const size_t off1 = off0 + 64;
    *(float4*)&Out[off0] = o0;
    *(float4*)&Out[off1] = o1;
    ushort4 q0, q1;
    q0.x = f2bf(o0.x); q0.y = f2bf(o0.y); q0.z = f2bf(o0.z); q0.w = f2bf(o0.w);
    q1.x = f2bf(o1.x); q1.y = f2bf(o1.y); q1.z = f2bf(o1.z); q1.w = f2bf(o1.w);
    *(ushort4*)&Outb[off0] = q0;
    *(ushort4*)&Outb[off1] = q1;
  }
}

// ---------------------------------------------------------------------------
// Screen: bf16 MFMA, one 128x128 tile per block (grid 64x64). Register
// epilogue: (a) Sc stored in FRAGMENT layout straight from acc (no Cs, no
// epilogue barriers); (b) 32-col group maxes via 16-lane shfl_xor max
// (order-independent -> t identical to round-5). tmaxT is [NQ][NROWS].
// Sc layout: tile(bx*64+by) * 16384 + (w*16+i*4+j)*256 + lane*4 + rg.
// ---------------------------------------------------------------------------
__global__ __launch_bounds__(256, 5)
void screen_store(const unsigned short* __restrict__ Ehb,
                  const unsigned short* __restrict__ Etb,
                  float* __restrict__ tmaxT, unsigned short* __restrict__ Sc) {
  __shared__ unsigned short As[BM * BK];   // 8 KB
  __shared__ unsigned short Bs[BN * BK];   // 8 KB

  const int tid = threadIdx.x;
  const int rowBase = blockIdx.x * BM;
  const int colBase = blockIdx.y * BN;
  const int w = tid >> 6, lane = tid & 63;
  const int q = lane >> 4, l15 = lane & 15;
  const int wr = (w & 1) * 64, wc = (w >> 1) * 64;

  const int c0 = tid, c1 = tid + 256;
  const int wb0 = __builtin_amdgcn_readfirstlane(tid & ~63);
  const int wb1 = wb0 + 256;
  const int ar0 = c0 >> 2, ac0 = (c0 & 3) * 8;
  const int ar1 = c1 >> 2, ac1 = (c1 & 3) * 8;

  f32x4 acc[4][4];
#pragma unroll
  for (int i = 0; i < 4; ++i)
#pragma unroll
    for (int j = 0; j < 4; ++j) acc[i][j] = (f32x4){0.f, 0.f, 0.f, 0.f};

  for (int kt = 0; kt < DIMK; kt += BK) {
    __syncthreads();
    gld16(Ehb + (size_t)(rowBase + ar0) * DIMK + kt + ac0, As + wb0 * 8);
    gld16(Ehb + (size_t)(rowBase + ar1) * DIMK + kt + ac1, As + wb1 * 8);
    gld16(Etb + (size_t)(colBase + ar0) * DIMK + kt + ac0, Bs + wb0 * 8);
    gld16(Etb + (size_t)(colBase + ar1) * DIMK + kt + ac1, Bs + wb1 * 8);
    __syncthreads();   // drains vmcnt (global_load_lds) + orders LDS

    bf16x8 af[4], bf[4];
#pragma unroll
    for (int i = 0; i < 4; ++i)
      af[i] = *(const bf16x8*)&As[(wr + i * 16 + l15) * BK + q * 8];
#pragma unroll
    for (int j = 0; j < 4; ++j)
      bf[j] = *(const bf16x8*)&Bs[(wc + j * 16 + l15) * BK + q * 8];
#pragma unroll
    for (int i = 0; i < 4; ++i)
#pragma unroll
      for (int j = 0; j < 4; ++j)
        acc[i][j] = __builtin_amdgcn_mfma_f32_16x16x32_bf16(af[i], bf[j], acc[i][j], 0, 0, 0);
  }

  // --- register epilogue (no barriers) ---
  const int tileId = blockIdx.x * 64 + blockIdx.y;
  unsigned short* scb = Sc + (size_t)tileId * 16384 + (size_t)(w * 16) * 256;
#pragma unroll
  for (int i = 0; i < 4; ++i)
#pragma unroll
    for (int j = 0; j < 4; ++j) {
      ushort4 ob;
      ob.x = f2bf(acc[i][j][0]); ob.y = f2bf(acc[i][j][1]);
      ob.z = f2bf(acc[i][j][2]); ob.w = f2bf(acc[i][j][3]);
      *(ushort4*)&scb[(i * 4 + j) * 256 + lane * 4] = ob;
    }

  // 32-col group maxes: combine j-pairs, reduce across the 16 l15 lanes.
#pragma unroll
  for (int i = 0; i < 4; ++i)
#pragma unroll
    for (int jp = 0; jp < 2; ++jp) {
      float m[4];
#pragma unroll
      for (int rg = 0; rg < 4; ++rg)
        m[rg] = fmaxf(acc[i][2 * jp][rg], acc[i][2 * jp + 1][rg]);
#pragma unroll
      for (int off = 1; off < 16; off <<= 1)
#pragma unroll
        for (int rg = 0; rg < 4; ++rg)
          m[rg] = fmaxf(m[rg], __shfl_xor(m[rg], off, 64));
      if (l15 == 0) {
        const int g = (colBase >> 5) + (w >> 1) * 2 + jp;       // global 32-col group
        const int ro = rowBase + wr + i * 16 + q * 4;           // 4 consecutive rows
        float4 o; o.x = m[0]; o.y = m[1]; o.z = m[2]; o.w = m[3];
        *(float4*)&tmaxT[(size_t)g * NROWS + ro] = o;
      }
    }
}

// ---------------------------------------------------------------------------
// Threshold: t[row] = (10th-best of 256 group maxes) - TMARGIN; zero cnt.
// tmaxT is [NQ][NROWS] -> reads coalesced across the 64 row-lanes.
// ---------------------------------------------------------------------------
__global__ __launch_bounds__(256)
void row_thresh(const float* __restrict__ tmaxT, float* __restrict__ t,
                int* __restrict__ cnt) {
  __shared__ float pv[64][4][TOPK];
  const int rloc = threadIdx.x & 63, part = threadIdx.x >> 6;
  const int row = blockIdx.x * 64 + rloc;

  float vals[TOPK];
#pragma unroll
  for (int s = 0; s < TOPK; ++s) vals[s] = -INFINITY;
  for (int g = part * 64; g < part * 64 + 64; ++g)
    tkv_insert<TOPK>(vals, tmaxT[(size_t)g * NROWS + row]);
#pragma unroll
  for (int s = 0; s < TOPK; ++s) pv[rloc][part][s] = vals[s];
  __syncthreads();
  if (part == 0) {
    float v2[TOPK];
#pragma unroll
    for (int s = 0; s < TOPK; ++s) v2[s] = -INFINITY;
    for (int p = 0; p < 4; ++p)
#pragma unroll
      for (int s = 0; s < TOPK; ++s) tkv_insert<TOPK>(v2, pv[rloc][p][s]);
    t[row] = v2[0] - TMARGIN;   // v2[0] = 10th best
    cnt[row] = 0;
  }
}

// ---------------------------------------------------------------------------
// Collect: memory-bound scan of fragment-layout Sc vs t[row]. Each thread
// reads one uint4 (8 bf16 = 2 source-lanes x 4 rows) and decodes (row,col).
// ---------------------------------------------------------------------------
__global__ __launch_bounds__(256)
void collect_scan(const unsigned short* __restrict__ Sc,
                  const float* __restrict__ t, int* __restrict__ cnt,
                  int* __restrict__ cand) {
  const long long gid = (long long)blockIdx.x * 256 + threadIdx.x;
  const long long F = gid * 8;                       // flat value index
  const int tileId = (int)(F >> 14);
  const int rem = (int)F & 16383;
  const int frag = rem >> 8;                         // w*16 + i*4 + j
  const int L = (rem & 255) >> 2;                    // even source lane
  const int w = frag >> 4, i = (frag >> 2) & 3, j = frag & 3;
  const int rbase = ((tileId >> 6) << 7) + (w & 1) * 64 + i * 16 + ((L >> 4) << 2);
  const int cb = ((tileId & 63) << 7) + (w >> 1) * 64 + j * 16 + (L & 15);

  const float4 t4 = *(const float4*)&t[rbase];
  const uint4 u = *(const uint4*)&Sc[F];
  const unsigned int uu[4] = {u.x, u.y, u.z, u.w};   // [L.rg01, L.rg23, L1.rg01, L1.rg23]
#pragma unroll
  for (int h = 0; h < 2; ++h) {                      // source lane L+h -> col cb+h
    const int col = cb + h;
#pragma unroll
    for (int d = 0; d < 2; ++d) {
      const unsigned int x = uu[h * 2 + d];
      const float lo = __uint_as_float(x << 16);                 // rg = 2d
      const float hi = __uint_as_float(x & 0xFFFF0000u);         // rg = 2d+1
      const float tl = (d == 0) ? t4.x : t4.z;
      const float th = (d == 0) ? t4.y : t4.w;
      if (lo >= tl) {
        const int p = atomicAdd(&cnt[rbase + 2 * d], 1);
        if (p < CAP) cand[(size_t)(rbase + 2 * d) * CAP + p] = col;
      }
      if (hi >= th) {
        const int p = atomicAdd(&cnt[rbase + 2 * d + 1], 1);
        if (p < CAP) cand[(size_t)(rbase + 2 * d + 1) * CAP + p] = col;
      }
    }
  }
}

// ---------------------------------------------------------------------------
// Rescore: arithmetic BIT-IDENTICAL to round-1's logits path (sequential
// fmaf chain k=0..511, then *SCALE). Thread per (row, slot).
// ---------------------------------------------------------------------------
__global__ __launch_bounds__(256)
void rescore_chain(const float* __restrict__ Eh, const float* __restrict__ Et,
                   const int* __restrict__ cnt, const int* __restrict__ cand,
                   float* __restrict__ pscore) {
  const int idx = blockIdx.x * 256 + threadIdx.x;     // [0, NROWS*CAP)
  const int r = idx >> 6, c = idx & (CAP - 1);
  if (c >= cnt[r]) return;
  const int cc = cand[(size_t)r * CAP + c];
  const float* a = Eh + (size_t)r * DIMK;
  const float* b = Et + (size_t)cc * DIMK;
  float p = 0.f;
#pragma unroll 4
  for (int k = 0; k < DIMK; k += 4) {
    const float4 av = *(const float4*)&a[k];
    const float4 bv = *(const float4*)&b[k];
    p = fmaf(av.x, bv.x, p);
    p = fmaf(av.y, bv.y, p);
    p = fmaf(av.z, bv.z, p);
    p = fmaf(av.w, bv.w, p);
  }
  pscore[idx] = p * SCALE;
}

// ---------------------------------------------------------------------------
// Finalize: top-10 of exact scores, softmax, emit edge list.
// Output layout (all fp32): [src N*K][dst N*K][weight N*K].
// ---------------------------------------------------------------------------
__global__ __launch_bounds__(256)
void finalize(const float* __restrict__ pscore, const int* __restrict__ cnt,
              const int* __restrict__ cand, float* __restrict__ out) {
  const int r = blockIdx.x * 256 + threadIdx.x;
  const int n = min(cnt[r], CAP);
  float vals[TOPK]; int idxs[TOPK];
#pragma unroll
  for (int s = 0; s < TOPK; ++s) { vals[s] = -INFINITY; idxs[s] = 0; }
  for (int c = 0; c < n; ++c)
    tk_insert<TOPK>(vals, idxs, pscore[(size_t)r * CAP + c],
                    cand[(size_t)r * CAP + c]);

  const float m = vals[TOPK - 1];
  float w[TOPK]; float sum = 0.f;
#pragma unroll
  for (int j = 0; j < TOPK; ++j) { w[j] = expf(vals[TOPK - 1 - j] - m); sum += w[j]; }
  const float inv = 1.0f / sum;

  const size_t ro = (size_t)r * TOPK;
#pragma unroll
  for (int j = 0; j < TOPK; ++j) {
    out[ro + j] = (float)r;                                         // src
    out[(size_t)NROWS * TOPK + ro + j] = (float)idxs[TOPK - 1 - j]; // dst
    out[2 * (size_t)NROWS * TOPK + ro + j] = w[j] * inv;            // weight
  }
}

// ---------------------------------------------------------------------------
extern "C" void kernel_launch(void* const* d_in, const int* in_sizes, int n_in,
                              void* d_out, int out_size, void* d_ws, size_t ws_size,
                              hipStream_t stream) {
  const float* X  = (const float*)d_in[0];
  const float* Wh = (const float*)d_in[1];
  const float* bh = (const float*)d_in[2];
  const float* Wt = (const float*)d_in[3];
  const float* bt = (const float*)d_in[4];
  float* out = (float*)d_out;

  char* ws = (char*)d_ws;
  const size_t embB  = (size_t)NROWS * DIMK * sizeof(float);          // 16 MB
  const size_t embBH = (size_t)NROWS * DIMK * sizeof(unsigned short); //  8 MB
  const size_t tmaxB = (size_t)NQ * NROWS * sizeof(float);            //  8 MB
  const size_t tB    = (size_t)NROWS * sizeof(float);                 // 32 KB
  const size_t cntB  = (size_t)NROWS * sizeof(int);                   // 32 KB
  const size_t candB = (size_t)NROWS * CAP * sizeof(int);             //  2 MB
  const size_t pscB  = (size_t)NROWS * CAP * sizeof(float);           //  2 MB
  float* Eh   = (float*)ws;
  float* Et   = (float*)(ws + embB);
  unsigned short* Ehb = (unsigned short*)(ws + 2 * embB);
  unsigned short* Etb = (unsigned short*)(ws + 2 * embB + embBH);
  float* tmaxT = (float*)(ws + 2 * embB + 2 * embBH);
  float* t    = (float*)(ws + 2 * embB + 2 * embBH + tmaxB);
  int*   cnt  = (int*)(ws + 2 * embB + 2 * embBH + tmaxB + tB);
  int*   cand = (int*)(ws + 2 * embB + 2 * embBH + tmaxB + tB + cntB);
  float* pscore = (float*)(ws + 2 * embB + 2 * embBH + tmaxB + tB + cntB + candB);
  unsigned short* Sc = (unsigned short*)
      (ws + 2 * embB + 2 * embBH + tmaxB + tB + cntB + candB + pscB);
  // total ws use ~190 MB (Sc = 128 MB), same budget as round 5 (worked)

  dim3 blk(NTHREADS);
  dim3 g1(NROWS / ETM, (2 * DIMK) / ETN);      // 64 x 8
  embed_gemm<<<g1, blk, 0, stream>>>(X, Wh, bh, Wt, bt, Eh, Et, Ehb, Etb);

  dim3 g2(NROWS / BM, NROWS / BN);             // 64 x 64, one tile per block
  screen_store<<<g2, blk, 0, stream>>>(Ehb, Etb, tmaxT, Sc);

  row_thresh<<<NROWS / 64, blk, 0, stream>>>(tmaxT, t, cnt);

  const int scanBlocks = (int)(((long long)NROWS * NROWS / 8) / 256);  // 32768
  collect_scan<<<scanBlocks, blk, 0, stream>>>(Sc, t, cnt, cand);

  rescore_chain<<<(NROWS * CAP) / 256, blk, 0, stream>>>(Eh, Et, cnt, cand, pscore);

  finalize<<<NROWS / 256, blk, 0, stream>>>(pscore, cnt, cand, out);
}

// Round 7
// 457.258 us; speedup vs baseline: 1.1409x; 1.1409x over previous
//
#include <hip/hip_runtime.h>
#include <math.h>

// Problem constants (reference: N=8192, DIM=512, TOPK=10, all fp32)
#define NROWS 8192
#define DIMK  512
#define TOPK  10
#define SCALE 0.044194173824159223f   // fp32(512**-0.5)

// Phase-1 embed GEMM tiling (fp32 VALU): 128x64 tile, 8x4 micro-tile.
#define ETM 128
#define ETN 64
#define ETK 32
#define NTHREADS 256

// Screen GEMM tiling (bf16 MFMA) — round-5 strip structure
#define BM 128
#define BN 128
#define BK 32
#define NS2 16                    // column strips for screen passes
#define SCOLS2 (NROWS / NS2)      // 512 cols per strip (4 tiles)
#define NQ 256                    // 32-col quarter-groups per row (8192/32)
#define CAP 64                    // max candidates per row
#define TMARGIN 2.0f              // bf16-gemm noise (~0.65) + bf16-storage (~0.35) << 2.0

typedef __attribute__((ext_vector_type(8))) short bf16x8;   // 8 bf16 = 4 VGPRs
typedef __attribute__((ext_vector_type(4))) float f32x4;

// ---------------------------------------------------------------------------
// Register-resident sorted top-K (ascending; vals[0] = running min).
// ---------------------------------------------------------------------------
template <int K>
__device__ __forceinline__ void tk_insert(float (&vals)[K], int (&idxs)[K],
                                          float v, int idx) {
  if (v > vals[0]) {
    vals[0] = v; idxs[0] = idx;
#pragma unroll
    for (int s = 0; s < K - 1; ++s) {
      const bool sw = vals[s] > vals[s + 1];
      const float tv = vals[s]; const int ti = idxs[s];
      vals[s]     = sw ? vals[s + 1] : vals[s];
      idxs[s]     = sw ? idxs[s + 1] : idxs[s];
      vals[s + 1] = sw ? tv : vals[s + 1];
      idxs[s + 1] = sw ? ti : idxs[s + 1];
    }
  }
}

template <int K>
__device__ __forceinline__ void tkv_insert(float (&vals)[K], float v) {
  if (v > vals[0]) {
    vals[0] = v;
#pragma unroll
    for (int s = 0; s < K - 1; ++s) {
      const bool sw = vals[s] > vals[s + 1];
      const float tv = vals[s];
      vals[s]     = sw ? vals[s + 1] : vals[s];
      vals[s + 1] = sw ? tv : vals[s + 1];
    }
  }
}

__device__ __forceinline__ unsigned short f2bf(float f) {   // RNE fp32->bf16
  unsigned int u = __float_as_uint(f);
  u = (u + 0x7FFF + ((u >> 16) & 1)) >> 16;
  return (unsigned short)u;
}

// async global->LDS, 16B per lane; lds ptr must be wave-uniform base
__device__ __forceinline__ void gld16(const void* g, const void* lds) {
  __builtin_amdgcn_global_load_lds(
      (const __attribute__((address_space(1))) void*)g,
      (__attribute__((address_space(3))) void*)lds, 16, 0, 0);
}

// ---------------------------------------------------------------------------
// Phase 1: E = X @ W^T + b (fp32 exact) + bf16 copies. 128x64 tile, 8x4
// micro-tile: LDS bytes/FLOP = 0.75 (vs 1.0 in the 64x64/4x4 version), acc
// is 32 VGPRs so no spill under (256,4). a-reads broadcast over 16 tx lanes;
// b-reads are 16 distinct 16-B addrs -> 2-way bank alias (free). Per-element
// k-chain stays sequential ascending fmaf + bias at end -> BIT-IDENTICAL
// Eh/Et vs rounds 3-5 (rank near-ties depend on it).
// ---------------------------------------------------------------------------
__global__ __launch_bounds__(NTHREADS, 4)
void embed_gemm(const float* __restrict__ X,
                const float* __restrict__ Wh, const float* __restrict__ bh,
                const float* __restrict__ Wt, const float* __restrict__ bt,
                float* __restrict__ Eh, float* __restrict__ Et,
                unsigned short* __restrict__ Ehb, unsigned short* __restrict__ Etb) {
  __shared__ float As[ETK][ETM + 4];   // d-major, 16.5 KB
  __shared__ float Bs[ETK][ETN + 4];   // 8.5 KB

  const int tid = threadIdx.x;
  const int rowBase = blockIdx.x * ETM;
  const int colBase = blockIdx.y * ETN;          // 0..960 over [Wh|Wt]
  const float* W  = (colBase < DIMK) ? Wh : Wt;
  const float* bb = (colBase < DIMK) ? bh : bt;
  float* Out            = (colBase < DIMK) ? Eh : Et;
  unsigned short* Outb  = (colBase < DIMK) ? Ehb : Etb;
  const int colOff = colBase & (DIMK - 1);

  const int tx = tid & 15, ty = tid >> 4;
  float acc[8][4];
#pragma unroll
  for (int r = 0; r < 8; ++r)
#pragma unroll
    for (int c = 0; c < 4; ++c) acc[r][c] = 0.f;

  for (int kt = 0; kt < DIMK; kt += ETK) {
    __syncthreads();   // WAR: previous iteration's reads done before restage
#pragma unroll
    for (int u = 0; u < 4; ++u) {      // A tile: 1024 float4
      const int idx = tid + u * NTHREADS;
      const int r = idx >> 3;          // 0..127
      const int dc = idx & 7;
      const float4 av = *(const float4*)&X[(size_t)(rowBase + r) * DIMK + kt + dc * 4];
      As[dc * 4 + 0][r] = av.x; As[dc * 4 + 1][r] = av.y;
      As[dc * 4 + 2][r] = av.z; As[dc * 4 + 3][r] = av.w;
    }
#pragma unroll
    for (int u = 0; u < 2; ++u) {      // B tile: 512 float4
      const int idx = tid + u * NTHREADS;
      const int r = idx >> 3;          // 0..63
      const int dc = idx & 7;
      const float4 bv = *(const float4*)&W[(size_t)(colOff + r) * DIMK + kt + dc * 4];
      Bs[dc * 4 + 0][r] = bv.x; Bs[dc * 4 + 1][r] = bv.y;
      Bs[dc * 4 + 2][r] = bv.z; Bs[dc * 4 + 3][r] = bv.w;
    }
    __syncthreads();
#pragma unroll 8
    for (int k = 0; k < ETK; ++k) {
      const float4 a0 = *(const float4*)&As[k][ty * 4];
      const float4 a1 = *(const float4*)&As[k][64 + ty * 4];
      const float4 b  = *(const float4*)&Bs[k][tx * 4];
      const float ar[8] = {a0.x, a0.y, a0.z, a0.w, a1.x, a1.y, a1.z, a1.w};
      const float br[4] = {b.x, b.y, b.z, b.w};
#pragma unroll
      for (int r = 0; r < 8; ++r)
#pragma unroll
        for (int c = 0; c < 4; ++c)
          acc[r][c] = fmaf(ar[r], br[c], acc[r][c]);
    }
  }

  const float4 bv = *(const float4*)&bb[colOff + tx * 4];
  const float br[4] = {bv.x, bv.y, bv.z, bv.w};
#pragma unroll
  for (int r = 0; r < 8; ++r) {
    const int row = rowBase + ((r < 4) ? (ty * 4 + r) : (64 + ty * 4 + r - 4));
    float4 o;
    o.x = acc[r][0] + br[0]; o.y = acc[r][1] + br[1];
    o.z = acc[r][2] + br[2]; o.w = acc[r][3] + br[3];
    const size_t off = (size_t)row * DIMK + colOff + tx * 4;
    *(float4*)&Out[off] = o;
    ushort4 ob;
    ob.x = f2bf(o.x); ob.y = f2bf(o.y); ob.z = f2bf(o.z); ob.w = f2bf(o.w);
    *(ushort4*)&Outb[off] = ob;
  }
}

// ---------------------------------------------------------------------------
// Screen pass (round-5, measured 157 us): bf16 MFMA GEMM; epilogue dumps each
// 128x64 half-tile to LDS, thread=(row, 32-col chunk) computes chunk max
// (-> tmax) AND stores 32 logits as bf16 to Sc (row-major, line-granular).
// ---------------------------------------------------------------------------
__global__ __launch_bounds__(256, 3)
void screen_store(const unsigned short* __restrict__ Ehb,
                  const unsigned short* __restrict__ Etb,
                  float* __restrict__ tmax, unsigned short* __restrict__ Sc) {
  __shared__ unsigned short As[BM * BK];   // 8 KB
  __shared__ unsigned short Bs[BN * BK];   // 8 KB
  __shared__ float Cs[BM][68];             // 34.8 KB; rows 16B-aligned

  const int tid = threadIdx.x;
  const int rowBase = blockIdx.x * BM;
  const int strip = blockIdx.y;
  const int w = tid >> 6, lane = tid & 63;
  const int q = lane >> 4, l15 = lane & 15;
  const int wr = (w & 1) * 64, wc = (w >> 1) * 64;
  const int rr = tid >> 1, hq = tid & 1;   // epilogue: row / 32-col chunk

  const int c0 = tid, c1 = tid + 256;
  const int wb0 = __builtin_amdgcn_readfirstlane(tid & ~63);
  const int wb1 = wb0 + 256;
  const int ar0 = c0 >> 2, ac0 = (c0 & 3) * 8;
  const int ar1 = c1 >> 2, ac1 = (c1 & 3) * 8;

  for (int ct = 0; ct < SCOLS2; ct += BN) {
    const int colBase = strip * SCOLS2 + ct;
    const int tileG = colBase >> 7;          // global 128-col tile index
    f32x4 acc[4][4];
#pragma unroll
    for (int i = 0; i < 4; ++i)
#pragma unroll
      for (int j = 0; j < 4; ++j) acc[i][j] = (f32x4){0.f, 0.f, 0.f, 0.f};

    for (int kt = 0; kt < DIMK; kt += BK) {
      __syncthreads();
      gld16(Ehb + (size_t)(rowBase + ar0) * DIMK + kt + ac0, As + wb0 * 8);
      gld16(Ehb + (size_t)(rowBase + ar1) * DIMK + kt + ac1, As + wb1 * 8);
      gld16(Etb + (size_t)(colBase + ar0) * DIMK + kt + ac0, Bs + wb0 * 8);
      gld16(Etb + (size_t)(colBase + ar1) * DIMK + kt + ac1, Bs + wb1 * 8);
      __syncthreads();   // drains vmcnt (global_load_lds) + orders LDS

      bf16x8 af[4], bf[4];
#pragma unroll
      for (int i = 0; i < 4; ++i)
        af[i] = *(const bf16x8*)&As[(wr + i * 16 + l15) * BK + q * 8];
#pragma unroll
      for (int j = 0; j < 4; ++j)
        bf[j] = *(const bf16x8*)&Bs[(wc + j * 16 + l15) * BK + q * 8];
#pragma unroll
      for (int i = 0; i < 4; ++i)
#pragma unroll
        for (int j = 0; j < 4; ++j)
          acc[i][j] = __builtin_amdgcn_mfma_f32_16x16x32_bf16(af[i], bf[j], acc[i][j], 0, 0, 0);
    }

    // Epilogue per 64-col half: dump -> (chunk max, bf16 store).
#pragma unroll
    for (int half = 0; half < 2; ++half) {
      if ((w >> 1) == half) {
#pragma unroll
        for (int i = 0; i < 4; ++i)
#pragma unroll
          for (int j = 0; j < 4; ++j)
#pragma unroll
            for (int rg = 0; rg < 4; ++rg)
              Cs[wr + i * 16 + q * 4 + rg][j * 16 + l15] = acc[i][j][rg];
      }
      __syncthreads();
      float m = -INFINITY;
      unsigned int pk[16];
#pragma unroll
      for (int k = 0; k < 8; ++k) {
        const f32x4 v = *(const f32x4*)&Cs[rr][hq * 32 + k * 4];
        m = fmaxf(m, fmaxf(fmaxf(v[0], v[1]), fmaxf(v[2], v[3])));
        pk[2 * k]     = (unsigned int)f2bf(v[0]) | ((unsigned int)f2bf(v[1]) << 16);
        pk[2 * k + 1] = (unsigned int)f2bf(v[2]) | ((unsigned int)f2bf(v[3]) << 16);
      }
      tmax[(size_t)(rowBase + rr) * NQ + tileG * 4 + half * 2 + hq] = m;
      unsigned int* dst = (unsigned int*)
          &Sc[(size_t)(rowBase + rr) * NROWS + colBase + half * 64 + hq * 32];
#pragma unroll
      for (int k = 0; k < 4; ++k)
        *(uint4*)&dst[k * 4] = make_uint4(pk[4*k], pk[4*k+1], pk[4*k+2], pk[4*k+3]);
      __syncthreads();   // readback done before next dump overwrites Cs
    }
  }
}

// ---------------------------------------------------------------------------
// Threshold: t[row] = (10th-best of 256 chunk maxes) - TMARGIN; zero cnt.
// ---------------------------------------------------------------------------
__global__ __launch_bounds__(256)
void row_thresh(const float* __restrict__ tmax, float* __restrict__ t,
                int* __restrict__ cnt) {
  __shared__ float pv[64][4][TOPK];
  const int rloc = threadIdx.x & 63, part = threadIdx.x >> 6;
  const int row = blockIdx.x * 64 + rloc;

  float vals[TOPK];
#pragma unroll
  for (int s = 0; s < TOPK; ++s) vals[s] = -INFINITY;
  const size_t base = (size_t)row * NQ + part * 64;
  for (int i = 0; i < 64; i += 4) {
    const f32x4 v = *(const f32x4*)&tmax[base + i];
#pragma unroll
    for (int e = 0; e < 4; ++e) tkv_insert<TOPK>(vals, v[e]);
  }
#pragma unroll
  for (int s = 0; s < TOPK; ++s) pv[rloc][part][s] = vals[s];
  __syncthreads();
  if (part == 0) {
    float v2[TOPK];
#pragma unroll
    for (int s = 0; s < TOPK; ++s) v2[s] = -INFINITY;
    for (int p = 0; p < 4; ++p)
#pragma unroll
      for (int s = 0; s < TOPK; ++s) tkv_insert<TOPK>(v2, pv[rloc][p][s]);
    t[row] = v2[0] - TMARGIN;   // v2[0] = 10th best
    cnt[row] = 0;
  }
}

// ---------------------------------------------------------------------------
// Collect: memory-bound scan of stored bf16 logits vs t[row].
// One wave per row; lane reads 16 B (8 bf16) per iter, coalesced.
// ---------------------------------------------------------------------------
__global__ __launch_bounds__(256)
void collect_scan(const unsigned short* __restrict__ Sc,
                  const float* __restrict__ t, int* __restrict__ cnt,
                  int* __restrict__ cand) {
  const int lane = threadIdx.x & 63;
  const int r = blockIdx.x * 4 + (threadIdx.x >> 6);
  const float tt = t[r];
  const unsigned short* row = Sc + (size_t)r * NROWS;

#pragma unroll 1
  for (int it = 0; it < NROWS / 512; ++it) {
    const int c0 = it * 512 + lane * 8;
    const uint4 u = *(const uint4*)&row[c0];
    const unsigned int uu[4] = {u.x, u.y, u.z, u.w};
#pragma unroll
    for (int e = 0; e < 4; ++e) {
      const float lo = __uint_as_float(uu[e] << 16);
      const float hi = __uint_as_float(uu[e] & 0xFFFF0000u);
      if (lo >= tt) {
        const int p = atomicAdd(&cnt[r], 1);
        if (p < CAP) cand[(size_t)r * CAP + p] = c0 + 2 * e;
      }
      if (hi >= tt) {
        const int p = atomicAdd(&cnt[r], 1);
        if (p < CAP) cand[(size_t)r * CAP + p] = c0 + 2 * e + 1;
      }
    }
  }
}

// ---------------------------------------------------------------------------
// Rescore: arithmetic BIT-IDENTICAL to round-1's logits path (sequential
// fmaf chain k=0..511, then *SCALE). Thread per (row, slot).
// ---------------------------------------------------------------------------
__global__ __launch_bounds__(256)
void rescore_chain(const float* __restrict__ Eh, const float* __restrict__ Et,
                   const int* __restrict__ cnt, const int* __restrict__ cand,
                   float* __restrict__ pscore) {
  const int idx = blockIdx.x * 256 + threadIdx.x;     // [0, NROWS*CAP)
  const int r = idx >> 6, c = idx & (CAP - 1);
  if (c >= cnt[r]) return;
  const int cc = cand[(size_t)r * CAP + c];
  const float* a = Eh + (size_t)r * DIMK;
  const float* b = Et + (size_t)cc * DIMK;
  float p = 0.f;
#pragma unroll 4
  for (int k = 0; k < DIMK; k += 4) {
    const float4 av = *(const float4*)&a[k];
    const float4 bv = *(const float4*)&b[k];
    p = fmaf(av.x, bv.x, p);
    p = fmaf(av.y, bv.y, p);
    p = fmaf(av.z, bv.z, p);
    p = fmaf(av.w, bv.w, p);
  }
  pscore[idx] = p * SCALE;
}

// ---------------------------------------------------------------------------
// Finalize: top-10 of exact scores, softmax, emit edge list.
// Output layout (all fp32): [src N*K][dst N*K][weight N*K].
// ---------------------------------------------------------------------------
__global__ __launch_bounds__(256)
void finalize(const float* __restrict__ pscore, const int* __restrict__ cnt,
              const int* __restrict__ cand, float* __restrict__ out) {
  const int r = blockIdx.x * 256 + threadIdx.x;
  const int n = min(cnt[r], CAP);
  float vals[TOPK]; int idxs[TOPK];
#pragma unroll
  for (int s = 0; s < TOPK; ++s) { vals[s] = -INFINITY; idxs[s] = 0; }
  for (int c = 0; c < n; ++c)
    tk_insert<TOPK>(vals, idxs, pscore[(size_t)r * CAP + c],
                    cand[(size_t)r * CAP + c]);

  const float m = vals[TOPK - 1];
  float w[TOPK]; float sum = 0.f;
#pragma unroll
  for (int j = 0; j < TOPK; ++j) { w[j] = expf(vals[TOPK - 1 - j] - m); sum += w[j]; }
  const float inv = 1.0f / sum;

  const size_t ro = (size_t)r * TOPK;
#pragma unroll
  for (int j = 0; j < TOPK; ++j) {
    out[ro + j] = (float)r;                                         // src
    out[(size_t)NROWS * TOPK + ro + j] = (float)idxs[TOPK - 1 - j]; // dst
    out[2 * (size_t)NROWS * TOPK + ro + j] = w[j] * inv;            // weight
  }
}

// ---------------------------------------------------------------------------
extern "C" void kernel_launch(void* const* d_in, const int* in_sizes, int n_in,
                              void* d_out, int out_size, void* d_ws, size_t ws_size,
                              hipStream_t stream) {
  const float* X  = (const float*)d_in[0];
  const float* Wh = (const float*)d_in[1];
  const float* bh = (const float*)d_in[2];
  const float* Wt = (const float*)d_in[3];
  const float* bt = (const float*)d_in[4];
  float* out = (float*)d_out;

  char* ws = (char*)d_ws;
  const size_t embB  = (size_t)NROWS * DIMK * sizeof(float);          // 16 MB
  const size_t embBH = (size_t)NROWS * DIMK * sizeof(unsigned short); //  8 MB
  const size_t tmaxB = (size_t)NROWS * NQ * sizeof(float);            //  8 MB
  const size_t tB    = (size_t)NROWS * sizeof(float);                 // 32 KB
  const size_t cntB  = (size_t)NROWS * sizeof(int);                   // 32 KB
  const size_t candB = (size_t)NROWS * CAP * sizeof(int);             //  2 MB
  const size_t pscB  = (size_t)NROWS * CAP * sizeof(float);           //  2 MB
  float* Eh   = (float*)ws;
  float* Et   = (float*)(ws + embB);
  unsigned short* Ehb = (unsigned short*)(ws + 2 * embB);
  unsigned short* Etb = (unsigned short*)(ws + 2 * embB + embBH);
  float* tmax = (float*)(ws + 2 * embB + 2 * embBH);
  float* t    = (float*)(ws + 2 * embB + 2 * embBH + tmaxB);
  int*   cnt  = (int*)(ws + 2 * embB + 2 * embBH + tmaxB + tB);
  int*   cand = (int*)(ws + 2 * embB + 2 * embBH + tmaxB + tB + cntB);
  float* pscore = (float*)(ws + 2 * embB + 2 * embBH + tmaxB + tB + cntB + candB);
  unsigned short* Sc = (unsigned short*)
      (ws + 2 * embB + 2 * embBH + tmaxB + tB + cntB + candB + pscB);
  // total ws use ~190 MB (Sc = 128 MB), same budget as rounds 5-6 (worked)

  dim3 blk(NTHREADS);
  dim3 g1(NROWS / ETM, (2 * DIMK) / ETN);      // 64 x 16
  embed_gemm<<<g1, blk, 0, stream>>>(X, Wh, bh, Wt, bt, Eh, Et, Ehb, Etb);

  dim3 g2(NROWS / BM, NS2);                    // 64 x 16 (strip structure)
  screen_store<<<g2, blk, 0, stream>>>(Ehb, Etb, tmax, Sc);

  row_thresh<<<NROWS / 64, blk, 0, stream>>>(tmax, t, cnt);

  collect_scan<<<NROWS / 4, blk, 0, stream>>>(Sc, t, cnt, cand);

  rescore_chain<<<(NROWS * CAP) / 256, blk, 0, stream>>>(Eh, Et, cnt, cand, pscore);

  finalize<<<NROWS / 256, blk, 0, stream>>>(pscore, cnt, cand, out);
}